// Round 1
// baseline (335.863 us; speedup 1.0000x reference)
//
#include <hip/hip_runtime.h>
#include <hip/hip_fp16.h>

typedef _Float16 f16x8 __attribute__((ext_vector_type(8)));
typedef float    f32x4 __attribute__((ext_vector_type(4)));

#define BATCH 131072

// ---------------------------------------------------------------------------
// Kernel 1: synthesize W_i[k][n] = tri(dist(p_i[k], p_{i+1}[n])) / sqrt(K),
// stored TRANSPOSED as Wt[n][k] in f16 so B-fragments read 8 contiguous k.
// ---------------------------------------------------------------------------
__global__ void synth_weights_kernel(const float* __restrict__ p0, const float* __restrict__ p1,
                                     const float* __restrict__ p2, const float* __restrict__ p3,
                                     _Float16* __restrict__ wt0, _Float16* __restrict__ wt1,
                                     _Float16* __restrict__ wt2)
{
    int idx = blockIdx.x * blockDim.x + threadIdx.x;   // 524288 total, exact grid
    const float* A; const float* B; _Float16* Wt; int K, N; float scl; int e;
    if (idx < 131072)      { A = p0; B = p1; Wt = wt0; K = 256; N = 512; scl = 0.0625f;              e = idx; }
    else if (idx < 393216) { A = p1; B = p2; Wt = wt1; K = 512; N = 512; scl = 0.04419417382415922f; e = idx - 131072; }
    else                   { A = p2; B = p3; Wt = wt2; K = 512; N = 256; scl = 0.04419417382415922f; e = idx - 393216; }
    int k = e / N;
    int n = e - k * N;
    float d2 = 0.f;
#pragma unroll
    for (int t = 0; t < 20; ++t) {
        float df = A[k * 20 + t] - B[n * 20 + t];
        d2 += df * df;
    }
    float d  = sqrtf(d2);
    float md = fmodf(d, 0.2f);                       // period 2P = 0.2, d >= 0
    float w  = 10.0f * (0.05f - fabsf(md - 0.1f)) * scl;  // == AMP/P*(P - |m-P| - P/2) / sqrt(K)
    Wt[(size_t)n * K + k] = (_Float16)w;
}

// ---------------------------------------------------------------------------
// Kernel 2..4: tiled GEMM  Out[M,N] = act(A[M,K] @ W[K,N] + bias)
//   A: row-major f16 (or f32 for layer 1, converted while staging)
//   W: given as Wt[n][k] row-major f16
//   128x128 block tile, BK=64, 4 waves (64x64 each), mfma_f32_16x16x32_f16.
//   LDS tiles are XOR-swizzled in 16B chunks: slot_chunk = chunk ^ (row&7).
//   global_load_lds writes linearly (base + lane*16); the SOURCE address is
//   pre-swizzled so the swizzled read is consistent (guide rule #21).
// ---------------------------------------------------------------------------
template<int KDIM, bool A_F32, bool RELU, bool OUT_F16>
__global__ __launch_bounds__(256)
void mlp_gemm_kernel(const void* __restrict__ Ap, const _Float16* __restrict__ Wt,
                     const float* __restrict__ bias, void* __restrict__ Outp, int N)
{
    constexpr int BM = 128, BN = 128, BK = 64;
    constexpr int KT = KDIM / BK;
    __shared__ _Float16 smA[BM * BK];   // [row][64] f16, 16 KB, swizzled chunks
    __shared__ _Float16 smB[BN * BK];   // [n-row][64] f16, 16 KB, swizzled chunks

    const int nb  = N / BN;
    const int bm  = blockIdx.x / nb;
    const int bn  = blockIdx.x - bm * nb;
    const int m0  = bm * BM, n0 = bn * BN;
    const int tid = threadIdx.x;
    const int lane = tid & 63;
    const int wid  = tid >> 6;
    const int wr = (wid >> 1) * 64;     // wave M offset
    const int wc = (wid & 1) * 64;      // wave N offset

    f32x4 acc[4][4] = {};

    // staging geometry: one issue = 64 lanes * 16B = 8 rows of 128B
    const int srow = lane >> 3;         // row within issue (== row&7)
    const int cs   = lane & 7;          // physical chunk slot
    const int cl   = cs ^ srow;         // logical chunk stored in this slot

    for (int kt = 0; kt < KT; ++kt) {
        // ---- stage A tile [BM][BK] ----
#pragma unroll
        for (int t = 0; t < 4; ++t) {
            const int issue = wid * 4 + t;
            const int row   = issue * 8 + srow;
            if constexpr (A_F32) {
                const float* src = (const float*)Ap + (size_t)(m0 + row) * KDIM + kt * BK + cl * 8;
                const float4 v0 = *(const float4*)(src);
                const float4 v1 = *(const float4*)(src + 4);
                f16x8 h;
                h[0] = (_Float16)v0.x; h[1] = (_Float16)v0.y; h[2] = (_Float16)v0.z; h[3] = (_Float16)v0.w;
                h[4] = (_Float16)v1.x; h[5] = (_Float16)v1.y; h[6] = (_Float16)v1.z; h[7] = (_Float16)v1.w;
                *(f16x8*)(&smA[row * BK + cs * 8]) = h;
            } else {
                const _Float16* src = (const _Float16*)Ap + (size_t)(m0 + row) * KDIM + kt * BK + cl * 8;
                __builtin_amdgcn_global_load_lds((const __attribute__((address_space(1))) void*)src,
                                                 (__attribute__((address_space(3))) void*)(&smA[issue * 512]),
                                                 16, 0, 0);
            }
        }
        // ---- stage B tile [BN][BK] from Wt ----
#pragma unroll
        for (int t = 0; t < 4; ++t) {
            const int issue = wid * 4 + t;
            const int row   = issue * 8 + srow;
            const _Float16* src = Wt + (size_t)(n0 + row) * KDIM + kt * BK + cl * 8;
            __builtin_amdgcn_global_load_lds((const __attribute__((address_space(1))) void*)src,
                                             (__attribute__((address_space(3))) void*)(&smB[issue * 512]),
                                             16, 0, 0);
        }
        __syncthreads();

        // ---- compute: 2 k-steps of 32, 16 MFMAs each ----
#pragma unroll
        for (int ks = 0; ks < BK / 32; ++ks) {
            f16x8 af[4], bf[4];
            const int cbase = ks * 4 + (lane >> 4);   // logical 16B chunk (8 f16) index
#pragma unroll
            for (int mi = 0; mi < 4; ++mi) {
                const int row = wr + mi * 16 + (lane & 15);
                af[mi] = *(const f16x8*)(&smA[row * BK + ((cbase ^ (row & 7)) << 3)]);
            }
#pragma unroll
            for (int ni = 0; ni < 4; ++ni) {
                const int row = wc + ni * 16 + (lane & 15);
                bf[ni] = *(const f16x8*)(&smB[row * BK + ((cbase ^ (row & 7)) << 3)]);
            }
#pragma unroll
            for (int mi = 0; mi < 4; ++mi)
#pragma unroll
                for (int ni = 0; ni < 4; ++ni)
                    acc[mi][ni] = __builtin_amdgcn_mfma_f32_16x16x32_f16(af[mi], bf[ni], acc[mi][ni], 0, 0, 0);
        }
        __syncthreads();
    }

    // ---- epilogue: bias (+relu), store f16 or f32 ----
    // C/D layout: col = lane&15, row = (lane>>4)*4 + q  [HW-verified]
#pragma unroll
    for (int ni = 0; ni < 4; ++ni) {
        const int n  = n0 + wc + ni * 16 + (lane & 15);
        const float bv = bias[n];
#pragma unroll
        for (int mi = 0; mi < 4; ++mi) {
#pragma unroll
            for (int q = 0; q < 4; ++q) {
                const int m = m0 + wr + mi * 16 + ((lane >> 4) << 2) + q;
                float v = acc[mi][ni][q] + bv;
                if constexpr (RELU) v = fmaxf(v, 0.0f);
                if constexpr (OUT_F16) ((_Float16*)Outp)[(size_t)m * N + n] = (_Float16)v;
                else                   ((float*)Outp)[(size_t)m * N + n] = v;
            }
        }
    }
}

// ---------------------------------------------------------------------------
// kernel_launch
//   ws layout: [wt0 512x256 f16 | wt1 512x512 f16 | wt2 256x512 f16 | z2 f16]
//   z1 (131072x512 f16 = 128 MB) aliases into d_out (131072x256 f32 = 128 MB).
// ---------------------------------------------------------------------------
extern "C" void kernel_launch(void* const* d_in, const int* in_sizes, int n_in,
                              void* d_out, int out_size, void* d_ws, size_t ws_size,
                              hipStream_t stream)
{
    const float* x  = (const float*)d_in[0];
    const float* p0 = (const float*)d_in[1];
    const float* p1 = (const float*)d_in[2];
    const float* p2 = (const float*)d_in[3];
    const float* p3 = (const float*)d_in[4];
    const float* b1 = (const float*)d_in[5];
    const float* b2 = (const float*)d_in[6];
    const float* b3 = (const float*)d_in[7];

    char* ws = (char*)d_ws;
    _Float16* wt0 = (_Float16*)(ws);                         // 262144 B
    _Float16* wt1 = (_Float16*)(ws + 262144);                // 524288 B
    _Float16* wt2 = (_Float16*)(ws + 262144 + 524288);       // 262144 B
    _Float16* z2  = (_Float16*)(ws + 1048576);               // 134217728 B
    _Float16* z1  = (_Float16*)d_out;                        // scratch alias (exact fit)

    synth_weights_kernel<<<2048, 256, 0, stream>>>(p0, p1, p2, p3, wt0, wt1, wt2);

    // L1: z1 = relu(x @ W0 + b1)      M=131072 K=256 N=512
    mlp_gemm_kernel<256, true,  true,  true ><<<(BATCH / 128) * (512 / 128), 256, 0, stream>>>(x,  wt0, b1, z1, 512);
    // L2: z2 = relu(z1 @ W1 + b2)     K=512 N=512
    mlp_gemm_kernel<512, false, true,  true ><<<(BATCH / 128) * (512 / 128), 256, 0, stream>>>(z1, wt1, b2, z2, 512);
    // L3: out = z2 @ W2 + b3 (f32)    K=512 N=256
    mlp_gemm_kernel<512, false, false, false><<<(BATCH / 128) * (256 / 128), 256, 0, stream>>>(z2, wt2, b3, d_out, 256);
}

// Round 2
// 232.101 us; speedup vs baseline: 1.4471x; 1.4471x over previous
//
#include <hip/hip_runtime.h>
#include <hip/hip_fp16.h>

typedef _Float16 f16x8 __attribute__((ext_vector_type(8)));
typedef float    f32x4 __attribute__((ext_vector_type(4)));

#define BATCH 131072

// ---------------------------------------------------------------------------
// Kernel 1: synthesize W_i[k][n] = tri(dist(p_i[k], p_{i+1}[n])) / sqrt(K),
// stored TRANSPOSED as Wt[n][k] f16 (B-fragments = 8 contiguous k per lane).
// ---------------------------------------------------------------------------
__global__ void synth_weights_kernel(const float* __restrict__ p0, const float* __restrict__ p1,
                                     const float* __restrict__ p2, const float* __restrict__ p3,
                                     _Float16* __restrict__ wt0, _Float16* __restrict__ wt1,
                                     _Float16* __restrict__ wt2)
{
    int idx = blockIdx.x * blockDim.x + threadIdx.x;   // 524288 total, exact grid
    const float* A; const float* B; _Float16* Wt; int K, N; float scl; int e;
    if (idx < 131072)      { A = p0; B = p1; Wt = wt0; K = 256; N = 512; scl = 0.0625f;              e = idx; }
    else if (idx < 393216) { A = p1; B = p2; Wt = wt1; K = 512; N = 512; scl = 0.04419417382415922f; e = idx - 131072; }
    else                   { A = p2; B = p3; Wt = wt2; K = 512; N = 256; scl = 0.04419417382415922f; e = idx - 393216; }
    int k = e / N;
    int n = e - k * N;
    float d2 = 0.f;
#pragma unroll
    for (int t = 0; t < 20; ++t) {
        float df = A[k * 20 + t] - B[n * 20 + t];
        d2 += df * df;
    }
    float d  = sqrtf(d2);
    float md = fmodf(d, 0.2f);                            // period 2P = 0.2, d >= 0
    float w  = 10.0f * (0.05f - fabsf(md - 0.1f)) * scl;  // AMP/P*(P-|m-P|-P/2)/sqrt(K)
    Wt[(size_t)n * K + k] = (_Float16)w;
}

// ---------------------------------------------------------------------------
// Fused MLP: one block = 128 batch rows through all 3 layers.
//   Activations live in a single 128 KB LDS buffer (f16), XOR-swizzled in
//   16B chunks: phys_chunk = chunk ^ (row & 7)  (conflict-free ds_read_b128).
//   Weights are read straight from L2 (global) as per-lane 16B B-fragments.
//   8 waves; wave tile = 128m x 64n (mi=8 -> max B reuse), acc 128 f32/lane.
// ---------------------------------------------------------------------------
template<int KT, int LDROW, int NI>
__device__ __forceinline__ void mm_phase(const char* lds, const _Float16* __restrict__ Wt,
                                         int nbase, int lane, f32x4 (&acc)[8][NI])
{
    const int rl = lane & 15;
    const int kc = lane >> 4;                 // k-chunk sub-index 0..3
    const _Float16* wp[NI];
#pragma unroll
    for (int ni = 0; ni < NI; ++ni)
        wp[ni] = Wt + (size_t)(nbase + ni * 16 + rl) * (KT * 32) + kc * 8;

    f16x8 bf[NI], bfn[NI];
#pragma unroll
    for (int ni = 0; ni < NI; ++ni) bf[ni] = *(const f16x8*)(wp[ni]);

#pragma unroll 2
    for (int ks = 0; ks < KT; ++ks) {
        if (ks + 1 < KT) {
#pragma unroll
            for (int ni = 0; ni < NI; ++ni)
                bfn[ni] = *(const f16x8*)(wp[ni] + (ks + 1) * 32);
        }
        f16x8 af[8];
#pragma unroll
        for (int mi = 0; mi < 8; ++mi) {
            const int row = mi * 16 + rl;
            const int ch  = (ks * 4 + kc) ^ (row & 7);
            af[mi] = *(const f16x8*)(lds + row * LDROW + (ch << 4));
        }
#pragma unroll
        for (int mi = 0; mi < 8; ++mi)
#pragma unroll
            for (int ni = 0; ni < NI; ++ni)
                acc[mi][ni] = __builtin_amdgcn_mfma_f32_16x16x32_f16(af[mi], bf[ni], acc[mi][ni], 0, 0, 0);
#pragma unroll
        for (int ni = 0; ni < NI; ++ni) bf[ni] = bfn[ni];
    }
}

// Write z (bias + optional relu, f32->f16) into LDS, row stride 1024 B, swizzled.
// D-fragment layout: col = lane&15, row = (lane>>4)*4 + q  [HW-verified]
template<int NI, bool RELU>
__device__ __forceinline__ void store_z_lds(char* lds, const float* __restrict__ bias,
                                            int nbase, int lane, f32x4 (&acc)[8][NI])
{
    const int rl = lane & 15;
    const int r4 = (lane >> 4) << 2;
#pragma unroll
    for (int ni = 0; ni < NI; ++ni) {
        const int n   = nbase + ni * 16 + rl;
        const float bv = bias[n];
        const int chx = n >> 3;
        const int nb2 = (n & 7) * 2;
#pragma unroll
        for (int mi = 0; mi < 8; ++mi) {
#pragma unroll
            for (int q = 0; q < 4; ++q) {
                const int m = mi * 16 + r4 + q;
                float v = acc[mi][ni][q] + bv;
                if (RELU) v = fmaxf(v, 0.0f);
                *(_Float16*)(lds + m * 1024 + ((chx ^ (m & 7)) << 4) + nb2) = (_Float16)v;
            }
        }
    }
}

__global__ __launch_bounds__(512, 2)
void fused_mlp_kernel(const float* __restrict__ x,
                      const _Float16* __restrict__ wt0, const _Float16* __restrict__ wt1,
                      const _Float16* __restrict__ wt2,
                      const float* __restrict__ b1, const float* __restrict__ b2,
                      const float* __restrict__ b3,
                      float* __restrict__ out)
{
    extern __shared__ char lds[];
    const int tid  = threadIdx.x;
    const int lane = tid & 63;
    const int w    = tid >> 6;
    const size_t m0 = (size_t)blockIdx.x * 128;

    // ---- phase 0: stage x slab f32 -> f16 into LDS [128 rows][512 B], swizzled
#pragma unroll
    for (int it = 0; it < 8; ++it) {
        const int c   = it * 512 + tid;
        const int row = c >> 5;
        const int c8  = c & 31;
        const float* src = x + (m0 + row) * 256 + c8 * 8;
        const float4 v0 = *(const float4*)src;
        const float4 v1 = *(const float4*)(src + 4);
        f16x8 h;
        h[0] = (_Float16)v0.x; h[1] = (_Float16)v0.y; h[2] = (_Float16)v0.z; h[3] = (_Float16)v0.w;
        h[4] = (_Float16)v1.x; h[5] = (_Float16)v1.y; h[6] = (_Float16)v1.z; h[7] = (_Float16)v1.w;
        *(f16x8*)(lds + row * 512 + ((c8 ^ (row & 7)) << 4)) = h;
    }
    __syncthreads();

    f32x4 acc[8][4];

    // ---- layer 1: z1 = relu(x @ W0 + b1)   [128,256]@[256,512]
#pragma unroll
    for (int mi = 0; mi < 8; ++mi)
#pragma unroll
        for (int ni = 0; ni < 4; ++ni) acc[mi][ni] = (f32x4){0.f, 0.f, 0.f, 0.f};
    mm_phase<8, 512, 4>(lds, wt0, w * 64, lane, acc);
    __syncthreads();                                   // all waves done reading x
    store_z_lds<4, true>(lds, b1, w * 64, lane, acc);  // z1 overwrites buffer
    __syncthreads();

    // ---- layer 2: z2 = relu(z1 @ W1 + b2)  [128,512]@[512,512]
#pragma unroll
    for (int mi = 0; mi < 8; ++mi)
#pragma unroll
        for (int ni = 0; ni < 4; ++ni) acc[mi][ni] = (f32x4){0.f, 0.f, 0.f, 0.f};
    mm_phase<16, 1024, 4>(lds, wt1, w * 64, lane, acc);
    __syncthreads();
    store_z_lds<4, true>(lds, b2, w * 64, lane, acc);
    __syncthreads();

    // ---- layer 3: out = z2 @ W2 + b3       [128,512]@[512,256], f32 out
    f32x4 acc3[8][2];
#pragma unroll
    for (int mi = 0; mi < 8; ++mi)
#pragma unroll
        for (int ni = 0; ni < 2; ++ni) acc3[mi][ni] = (f32x4){0.f, 0.f, 0.f, 0.f};
    mm_phase<16, 1024, 2>(lds, wt2, w * 32, lane, acc3);

    const int rl = lane & 15;
    const int r4 = (lane >> 4) << 2;
#pragma unroll
    for (int ni = 0; ni < 2; ++ni) {
        const int n = w * 32 + ni * 16 + rl;
        const float bv = b3[n];
#pragma unroll
        for (int mi = 0; mi < 8; ++mi) {
#pragma unroll
            for (int q = 0; q < 4; ++q) {
                const size_t m = m0 + mi * 16 + r4 + q;
                out[m * 256 + n] = acc3[mi][ni][q] + bv;
            }
        }
    }
}

// ---------------------------------------------------------------------------
// kernel_launch — ws: [wt0 512x256 f16 | wt1 512x512 f16 | wt2 256x512 f16]
// ---------------------------------------------------------------------------
extern "C" void kernel_launch(void* const* d_in, const int* in_sizes, int n_in,
                              void* d_out, int out_size, void* d_ws, size_t ws_size,
                              hipStream_t stream)
{
    const float* x  = (const float*)d_in[0];
    const float* p0 = (const float*)d_in[1];
    const float* p1 = (const float*)d_in[2];
    const float* p2 = (const float*)d_in[3];
    const float* p3 = (const float*)d_in[4];
    const float* b1 = (const float*)d_in[5];
    const float* b2 = (const float*)d_in[6];
    const float* b3 = (const float*)d_in[7];

    char* ws = (char*)d_ws;
    _Float16* wt0 = (_Float16*)(ws);                    // 262144 B
    _Float16* wt1 = (_Float16*)(ws + 262144);           // 524288 B
    _Float16* wt2 = (_Float16*)(ws + 262144 + 524288);  // 262144 B

    synth_weights_kernel<<<2048, 256, 0, stream>>>(p0, p1, p2, p3, wt0, wt1, wt2);

    fused_mlp_kernel<<<BATCH / 128, 512, 131072, stream>>>(x, wt0, wt1, wt2, b1, b2, b3,
                                                           (float*)d_out);
}